// Round 3
// baseline (382.972 us; speedup 1.0000x reference)
//
#include <hip/hip_runtime.h>
#include <hip/hip_bf16.h>
#include <math.h>

#define NN 50000
#define EE 800000
#define DIN 128
#define HEADS 8
#define DH 16
#define DOUT 16
#define NEG 0.2f
#define GM 32       // nodes per GEMM block
#define GB ((NN + GM - 1) / GM)     // 1563 gemm blocks
#define NB ((NN + 255) / 256)       // 196 init blocks
#define DEGB ((EE / 4 + 255) / 256) // 782 edge-quad chunks
#define NPART 8                     // one dst-range per XCD (blockIdx%8 ~ XCD, round-robin dispatch)
#define RANGE (NN / NPART)          // 6250 dst nodes per range
#define FILLB (DEGB * NPART)        // 6256 fill blocks
#define PAD 64      // padded CSR row slots; deg ~ Poisson(16), P(deg>=64) ~ 2e-18/node

typedef __attribute__((ext_vector_type(8))) short bf16x8;
typedef __attribute__((ext_vector_type(4))) float f32x4;
typedef __attribute__((ext_vector_type(2))) float f32x2;
typedef __attribute__((ext_vector_type(4))) int i32x4;

__device__ __forceinline__ unsigned pack2bf(float a, float b) {
    union { __hip_bfloat162 h; unsigned u; } c;
    c.h = __float22bfloat162_rn(make_float2(a, b));
    return c.u;
}
__device__ __forceinline__ unsigned short f2bf(float v) {
    union { __hip_bfloat16 h; unsigned short u; } c;
    c.h = __float2bfloat16(v);
    return c.u;
}
__device__ __forceinline__ float bflo(unsigned u) { return __uint_as_float(u << 16); }
__device__ __forceinline__ float bfhi(unsigned u) { return __uint_as_float(u & 0xffff0000u); }

// ---------- init: cnt=1 + self-loop (0..NB) || Wb1 cvt (NB..NB+128) || Wb2 cvt (last 16) ----------
__global__ __launch_bounds__(256) void init_wcvt(int* __restrict__ cnt,
                                                 unsigned short* __restrict__ esrcPad,
                                                 const float* __restrict__ Wl,
                                                 const float* __restrict__ Wr,
                                                 unsigned short* __restrict__ Wb,
                                                 const float* __restrict__ Wl2,
                                                 const float* __restrict__ Wr2,
                                                 unsigned short* __restrict__ Wb2) {
    int b = blockIdx.x, t = threadIdx.x;
    if (b < NB) {
        int i = b * 256 + t;
        if (i < NN) {
            cnt[i] = 1;                    // slot 0 = self-loop
            esrcPad[(size_t)i * PAD] = (unsigned short)i;
        }
    } else if (b < NB + 128) {
        int i = (b - NB) * 256 + t;   // 32768 entries
        int n = i >> 7, k = i & 127;
        float v = (n < 128) ? Wl[k * 128 + n] : Wr[k * 128 + (n - 128)];
        Wb[i] = f2bf(v);
    } else {
        int i = (b - NB - 128) * 256 + t;  // 4096 entries: Wb2[n][k], n in [0,32)
        int n = i >> 7, k = i & 127;
        float v = (n < 16) ? Wl2[k * 16 + n] : Wr2[k * 16 + (n - 16)];
        Wb2[i] = f2bf(v);
    }
}

// ---------- fused: XCD-partitioned padded fill (blocks 0..FILLB) || gemm1 MFMA (FILLB..FILLB+GB) ----------
// Fill FIRST: its atomic/scatter latency stream starts at t=0, gemm1's dense MFMA backfills.
// Partition: block b handles edge-chunk b>>3, but ONLY edges with dst in range (b&7).
// Round-robin block->XCD puts range r's esrcPad slice (0.8 MB u16) + cnt slice in ONE XCD's L2.
// gemm1 path is fully nontemporal (nt x loads, nt xlb/xr stores) so its ~64 MB stream
// no longer evicts the fill's scatter lines -> writebacks coalesce in L2.
// Output layouts are slice-major [head][node][16] for l1's head-partitioned gathers.
__global__ __launch_bounds__(256) void fill_gemm1(const int* __restrict__ ei,
                                                  int* __restrict__ cnt,
                                                  unsigned short* __restrict__ esrcPad,
                                                  const float* __restrict__ x,
                                                  const unsigned short* __restrict__ Wb,
                                                  unsigned short* __restrict__ xlb,
                                                  float* __restrict__ xr) {
    __shared__ unsigned short As[GM][136];   // gemm1 path only; pad 128->136
    int t = threadIdx.x;
    if (blockIdx.x < FILLB) {   // ---- fill path ----
        int chunk = blockIdx.x >> 3;
        int r = blockIdx.x & 7;          // dst-range == heuristic XCD id
        int i = chunk * 256 + t;
        if (i >= EE / 4) return;
        i32x4 ss = __builtin_nontemporal_load(((const i32x4*)ei) + i);
        i32x4 dd = __builtin_nontemporal_load(((const i32x4*)(ei + EE)) + i);
        int lo = r * RANGE;
        int p;
        if ((unsigned)(dd[0] - lo) < RANGE) {
            p = atomicAdd(&cnt[dd[0]], 1);
            esrcPad[(size_t)dd[0] * PAD + p] = (unsigned short)ss[0];
        }
        if ((unsigned)(dd[1] - lo) < RANGE) {
            p = atomicAdd(&cnt[dd[1]], 1);
            esrcPad[(size_t)dd[1] * PAD + p] = (unsigned short)ss[1];
        }
        if ((unsigned)(dd[2] - lo) < RANGE) {
            p = atomicAdd(&cnt[dd[2]], 1);
            esrcPad[(size_t)dd[2] * PAD + p] = (unsigned short)ss[2];
        }
        if ((unsigned)(dd[3] - lo) < RANGE) {
            p = atomicAdd(&cnt[dd[3]], 1);
            esrcPad[(size_t)dd[3] * PAD + p] = (unsigned short)ss[3];
        }
        return;
    }
    // ---- gemm1 path: 32 nodes x 256 cols, 4 waves; m89-verified 16x16x32 bf16 layouts ----
    int n0 = (blockIdx.x - FILLB) * GM;
    {   // stage: 32 rows x 128 ch fp32 -> bf16 LDS (nt: read-once, keep L2 for scatter)
        int row = t >> 3, seg = t & 7;
        int nsrc = n0 + row < NN ? n0 + row : NN - 1;   // clamp: safe read, store guarded
        const f32x4* xp = (const f32x4*)(x + (size_t)nsrc * DIN + 16 * seg);
        f32x4 v0 = __builtin_nontemporal_load(xp);
        f32x4 v1 = __builtin_nontemporal_load(xp + 1);
        f32x4 v2 = __builtin_nontemporal_load(xp + 2);
        f32x4 v3 = __builtin_nontemporal_load(xp + 3);
        uint4 p0 = make_uint4(pack2bf(v0[0], v0[1]), pack2bf(v0[2], v0[3]),
                              pack2bf(v1[0], v1[1]), pack2bf(v1[2], v1[3]));
        uint4 p1 = make_uint4(pack2bf(v2[0], v2[1]), pack2bf(v2[2], v2[3]),
                              pack2bf(v3[0], v3[1]), pack2bf(v3[2], v3[3]));
        *(uint4*)&As[row][16 * seg]     = p0;
        *(uint4*)&As[row][16 * seg + 8] = p1;
    }
    __syncthreads();
    int lane = t & 63, w = t >> 6;
    int m = lane & 15, quad = lane >> 4;
    f32x4 acc[2][4];
#pragma unroll
    for (int mt = 0; mt < 2; ++mt)
#pragma unroll
        for (int nt = 0; nt < 4; ++nt) acc[mt][nt] = (f32x4){0.f, 0.f, 0.f, 0.f};
#pragma unroll
    for (int ks = 0; ks < 4; ++ks) {
        int k = 32 * ks + 8 * quad;
        bf16x8 a0 = *(const bf16x8*)&As[m][k];
        bf16x8 a1 = *(const bf16x8*)&As[16 + m][k];
#pragma unroll
        for (int nt = 0; nt < 4; ++nt) {
            int n = 64 * w + 16 * nt + m;
            bf16x8 b = *(const bf16x8*)(Wb + (size_t)n * 128 + k);
            acc[0][nt] = __builtin_amdgcn_mfma_f32_16x16x32_bf16(a0, b, acc[0][nt], 0, 0, 0);
            acc[1][nt] = __builtin_amdgcn_mfma_f32_16x16x32_bf16(a1, b, acc[1][nt], 0, 0, 0);
        }
    }
    // stores: slice-major [head][node][16]; m == channel within head; nt stores (read later via L3->L2)
#pragma unroll
    for (int mt = 0; mt < 2; ++mt) {
#pragma unroll
        for (int nt = 0; nt < 4; ++nt) {
            int rbase = n0 + 16 * mt + 4 * quad;
            if (w < 2) {            // cols [0,128): xlb head h = 4w+nt, ch m
                int h = 4 * w + nt;
#pragma unroll
                for (int r = 0; r < 4; ++r) {
                    int row = rbase + r;
                    if (row < NN)
                        __builtin_nontemporal_store(f2bf(acc[mt][nt][r]),
                            &xlb[((size_t)h * NN + row) * 16 + m]);
                }
            } else {                // cols [128,256): xr head h = 4(w-2)+nt, ch m
                int h = 4 * (w - 2) + nt;
#pragma unroll
                for (int r = 0; r < 4; ++r) {
                    int row = rbase + r;
                    if (row < NN)
                        __builtin_nontemporal_store(acc[mt][nt][r],
                            &xr[((size_t)h * NN + row) * 16 + m]);
                }
            }
        }
    }
}

// ---------- layer-1 fused, HEAD-PARTITIONED: one wave per (head,dst) ----------
// head = blockIdx&7 -> round-robin XCD pinning: each XCD gathers only its 1.6 MB xlb slice
// (L2-resident) instead of the full 12.8 MB from L3. 8 lanes/edge (2 bf16 ch per lane),
// 8 edges per wave-iteration. esrcPad/xr reads are nt (streamed, don't evict the slice).
__global__ __launch_bounds__(256) void l1_fused(const unsigned short* __restrict__ esrcPad,
                                                const int* __restrict__ cnt,
                                                const unsigned short* __restrict__ xlb,
                                                const float* __restrict__ xr,
                                                const float* __restrict__ att,
                                                const float* __restrict__ bias,
                                                unsigned short* __restrict__ hb) {
    int h = blockIdx.x & 7;
    int d = (blockIdx.x >> 3) * 4 + (threadIdx.x >> 6);   // NN % 4 == 0
    int lane = threadIdx.x & 63;
    int e  = lane >> 3;      // edge octet 0..7
    int c2 = lane & 7;       // channel pair 0..7 (ch 2*c2, 2*c2+1)
    const unsigned short* xlbH = xlb + (size_t)h * NN * 16;
    const float* xrH = xr + (size_t)h * NN * 16;
    f32x2 xrv = __builtin_nontemporal_load(((const f32x2*)(xrH + (size_t)d * 16)) + c2);
    float2 atv = ((const float2*)(att + (size_t)h * 16))[c2];
    int rs = d * PAD;
    int re = rs + cnt[d];    // cnt >= 1 (self-loop)
    int last = re - 1;
    float acc0 = 0.f, acc1 = 0.f, l = 0.f;
    int slot = rs + e;
    int ci = slot < last ? slot : last;
    int s0 = __builtin_nontemporal_load(&esrcPad[ci]);
    for (; slot < re; slot += 8) {
        int ni = slot + 8 < last ? slot + 8 : last;
        int s1 = __builtin_nontemporal_load(&esrcPad[ni]);   // prefetch next
        unsigned u = ((const unsigned*)(xlbH + (size_t)s0 * 16))[c2];
        s0 = s1;
        float f0 = bflo(u), f1 = bfhi(u);
        float v0 = f0 + xrv[0]; v0 = fmaxf(v0, NEG * v0);
        float v1 = f1 + xrv[1]; v1 = fmaxf(v1, NEG * v1);
        float w = atv.x * v0 + atv.y * v1;
        w += __shfl_xor(w, 1);
        w += __shfl_xor(w, 2);
        w += __shfl_xor(w, 4);   // full 16-ch head logit within octet
        float p = __expf(w);
        acc0 += p * f0; acc1 += p * f1; l += p;
    }
#pragma unroll
    for (int off = 8; off < 64; off <<= 1) {
        acc0 += __shfl_xor(acc0, off);
        acc1 += __shfl_xor(acc1, off);
        l    += __shfl_xor(l, off);
    }
    if (e == 0) {
        float inv = 1.f / l;
        float2 bs = ((const float2*)(bias + (size_t)h * 16))[c2];
        float o0 = acc0 * inv + bs.x; o0 = o0 > 0.f ? o0 : expm1f(o0);
        float o1 = acc1 * inv + bs.y; o1 = o1 > 0.f ? o1 : expm1f(o1);
        ((unsigned*)(hb + ((size_t)h * NN + d) * 16))[c2] = pack2bf(o0, o1);
    }
}

// ---------- layer-2 GEMM via MFMA: [xl2 | xr2] = hb @ [Wl2 | Wr2] ----------
// hb is slice-major [head][node][16]; staging gathers 8x32B per row (k order = h*16+c,
// matching Wb2's k). 32 nodes x 32 cols per block, 4 waves.
__global__ __launch_bounds__(256) void gemm2(const unsigned short* __restrict__ hb,
                                             const unsigned short* __restrict__ Wb2,
                                             float* __restrict__ xl2, float* __restrict__ xr2) {
    __shared__ unsigned short As[GM][136];
    int t = threadIdx.x;
    int n0 = blockIdx.x * GM;
    {   // stage: thread (s8=head, row): 32B slice -> As[row][16*s8..]
        int s8 = t >> 5, row = t & 31;
        int nsrc = n0 + row < NN ? n0 + row : NN - 1;
        const uint4* src = (const uint4*)(hb + ((size_t)s8 * NN + nsrc) * 16);
        *(uint4*)&As[row][16 * s8]     = src[0];
        *(uint4*)&As[row][16 * s8 + 8] = src[1];
    }
    __syncthreads();
    int lane = t & 63, w = t >> 6;
    int m = lane & 15, quad = lane >> 4;
    int mt = w & 1, nt = w >> 1;
    f32x4 acc = (f32x4){0.f, 0.f, 0.f, 0.f};
#pragma unroll
    for (int ks = 0; ks < 4; ++ks) {
        int k = 32 * ks + 8 * quad;
        bf16x8 a = *(const bf16x8*)&As[16 * mt + m][k];
        bf16x8 b = *(const bf16x8*)(Wb2 + (size_t)(16 * nt + m) * 128 + k);
        acc = __builtin_amdgcn_mfma_f32_16x16x32_bf16(a, b, acc, 0, 0, 0);
    }
    // D: col=lane&15 (n within tile), row=quad*4+r (m within tile)
    float* __restrict__ dst = (nt == 0) ? xl2 : xr2;
#pragma unroll
    for (int r = 0; r < 4; ++r) {
        int node = n0 + 16 * mt + 4 * quad + r;
        if (node < NN) dst[(size_t)node * DOUT + m] = acc[r];
    }
}

// ---------- layer-2 fused: softmax + gather + bias + log_softmax ----------
__global__ __launch_bounds__(256) void l2_fused(const unsigned short* __restrict__ esrcPad,
                                                const int* __restrict__ cnt,
                                                const float* __restrict__ xl,
                                                const float* __restrict__ xr,
                                                const float* __restrict__ att,
                                                const float* __restrict__ bias,
                                                float* __restrict__ out) {
    int d = blockIdx.x * 4 + (threadIdx.x >> 6);    // NN % 4 == 0
    int lane = threadIdx.x & 63;
    int sl = lane >> 2;     // edge slot group 0..15
    int q = lane & 3;       // channel quad
    int rs = d * PAD;
    int re = rs + cnt[d];
    int last = re - 1;
    float4 xrq = ((const float4*)(xr + (size_t)d * DOUT))[q];
    float4 atq = ((const float4*)att)[q];
    float4 acc = make_float4(0.f, 0.f, 0.f, 0.f);
    float l = 0.f;
    int slot = rs + sl;
    int c0 = slot < last ? slot : last;
    int s0 = esrcPad[c0];
    for (; slot < re; slot += 16) {
        int c1 = slot + 16 < last ? slot + 16 : last;
        int s1 = esrcPad[c1];
        float4 cur = ((const float4*)(xl + (size_t)s0 * DOUT))[q];
        s0 = s1;
        float v0 = cur.x + xrq.x; v0 = fmaxf(v0, NEG * v0);
        float v1 = cur.y + xrq.y; v1 = fmaxf(v1, NEG * v1);
        float v2 = cur.z + xrq.z; v2 = fmaxf(v2, NEG * v2);
        float v3 = cur.w + xrq.w; v3 = fmaxf(v3, NEG * v3);
        float w = atq.x * v0 + atq.y * v1 + atq.z * v2 + atq.w * v3;
        w += __shfl_xor(w, 1);
        w += __shfl_xor(w, 2);          // full 16-ch logit
        float p = __expf(w);
        acc.x += p * cur.x; acc.y += p * cur.y;
        acc.z += p * cur.z; acc.w += p * cur.w;
        l += p;
    }
#pragma unroll
    for (int off = 4; off < 64; off <<= 1) {
        acc.x += __shfl_xor(acc.x, off);
        acc.y += __shfl_xor(acc.y, off);
        acc.z += __shfl_xor(acc.z, off);
        acc.w += __shfl_xor(acc.w, off);
        l += __shfl_xor(l, off);
    }
    float inv = 1.f / l;
    float4 b = ((const float4*)bias)[q];
    float4 v;
    v.x = acc.x * inv + b.x; v.y = acc.y * inv + b.y;
    v.z = acc.z * inv + b.z; v.w = acc.w * inv + b.w;
    float m = fmaxf(fmaxf(v.x, v.y), fmaxf(v.z, v.w));
    m = fmaxf(m, __shfl_xor(m, 1));
    m = fmaxf(m, __shfl_xor(m, 2));
    float es = __expf(v.x - m) + __expf(v.y - m) + __expf(v.z - m) + __expf(v.w - m);
    es += __shfl_xor(es, 1);
    es += __shfl_xor(es, 2);
    float lse = m + __logf(es);
    if (sl == 0) {
        ((float4*)(out + (size_t)d * DOUT))[q] = v;
        float4 ls;
        ls.x = v.x - lse; ls.y = v.y - lse; ls.z = v.z - lse; ls.w = v.w - lse;
        ((float4*)(out + (size_t)NN * DOUT + (size_t)d * DOUT))[q] = ls;
    }
}

extern "C" void kernel_launch(void* const* d_in, const int* in_sizes, int n_in,
                              void* d_out, int out_size, void* d_ws, size_t ws_size,
                              hipStream_t stream) {
    const float* x     = (const float*)d_in[0];
    const int*   ei    = (const int*)d_in[1];
    const float* Wl1   = (const float*)d_in[2];
    const float* Wr1   = (const float*)d_in[3];
    const float* att1  = (const float*)d_in[4];
    const float* bias1 = (const float*)d_in[5];
    const float* Wl2   = (const float*)d_in[6];
    const float* Wr2   = (const float*)d_in[7];
    const float* att2  = (const float*)d_in[8];
    const float* bias2 = (const float*)d_in[9];
    float* out = (float*)d_out;

    // ---- workspace layout (xr1/xlb/hb are slice-major [head][node][16]) ----
    float* xr1    = (float*)d_ws;                    // 8*NN*16 fp32
    float* xl2    = xr1 + (size_t)NN * DIN;          // NN*16
    float* xr2    = xl2 + (size_t)NN * DOUT;         // NN*16
    unsigned short* xlb = (unsigned short*)(xr2 + (size_t)NN * DOUT); // 8*NN*16 bf16
    unsigned short* hb  = xlb + (size_t)NN * DIN;    // 8*NN*16 bf16
    unsigned short* Wb  = hb + (size_t)NN * DIN;     // 256*128 bf16
    unsigned short* Wb2 = Wb + 256 * 128;            // 32*128 bf16
    unsigned short* esrcPad = Wb2 + 32 * 128;        // NN*64 padded CSR (u16: src < 50000 < 65536)
    int*   cnt    = (int*)(esrcPad + (size_t)NN * PAD);  // NN (byte offset multiple of 4)

    const int B = 256;
    init_wcvt<<<NB + 144, B, 0, stream>>>(cnt, esrcPad, Wl1, Wr1, Wb, Wl2, Wr2, Wb2);
    fill_gemm1<<<FILLB + GB, B, 0, stream>>>(ei, cnt, esrcPad, x, Wb, xlb, xr1);

    l1_fused<<<(NN / 4) * 8, B, 0, stream>>>(esrcPad, cnt, xlb, xr1, att1, bias1, hb);

    gemm2<<<GB, B, 0, stream>>>(hb, Wb2, xl2, xr2);

    l2_fused<<<NN / 4, B, 0, stream>>>(esrcPad, cnt, xl2, xr2, att2, bias2, out);
}

// Round 4
// 232.831 us; speedup vs baseline: 1.6448x; 1.6448x over previous
//
#include <hip/hip_runtime.h>
#include <hip/hip_bf16.h>
#include <math.h>

#define NN 50000
#define EE 800000
#define DIN 128
#define HEADS 8
#define DH 16
#define DOUT 16
#define NEG 0.2f
#define GM 32       // nodes per GEMM block
#define GB ((NN + GM - 1) / GM)     // 1563 gemm blocks
#define NB ((NN + 255) / 256)       // 196 init blocks
#define DEGB ((EE / 4 + 255) / 256) // 782 edge-quad chunks
#define NPART 8                     // one dst-range per XCD (blockIdx%8 ~ XCD, round-robin dispatch)
#define RANGE (NN / NPART)          // 6250 dst nodes per range
#define FILLB (DEGB * NPART)        // 6256 fill blocks
#define PAD 64      // padded CSR row slots; deg ~ Poisson(16), P(deg>=64) ~ 2e-18/node

typedef __attribute__((ext_vector_type(8))) short bf16x8;
typedef __attribute__((ext_vector_type(4))) float f32x4;
typedef __attribute__((ext_vector_type(4))) int i32x4;

__device__ __forceinline__ unsigned pack2bf(float a, float b) {
    union { __hip_bfloat162 h; unsigned u; } c;
    c.h = __float22bfloat162_rn(make_float2(a, b));
    return c.u;
}
__device__ __forceinline__ unsigned short f2bf(float v) {
    union { __hip_bfloat16 h; unsigned short u; } c;
    c.h = __float2bfloat16(v);
    return c.u;
}
__device__ __forceinline__ float bflo(unsigned u) { return __uint_as_float(u << 16); }
__device__ __forceinline__ float bfhi(unsigned u) { return __uint_as_float(u & 0xffff0000u); }

// ---------- init: cnt=1 + self-loop (0..NB) || Wb1 cvt (NB..NB+128) || Wb2 cvt (last 16) ----------
__global__ __launch_bounds__(256) void init_wcvt(int* __restrict__ cnt,
                                                 unsigned short* __restrict__ esrcPad,
                                                 const float* __restrict__ Wl,
                                                 const float* __restrict__ Wr,
                                                 unsigned short* __restrict__ Wb,
                                                 const float* __restrict__ Wl2,
                                                 const float* __restrict__ Wr2,
                                                 unsigned short* __restrict__ Wb2) {
    int b = blockIdx.x, t = threadIdx.x;
    if (b < NB) {
        int i = b * 256 + t;
        if (i < NN) {
            cnt[i] = 1;                    // slot 0 = self-loop
            esrcPad[(size_t)i * PAD] = (unsigned short)i;
        }
    } else if (b < NB + 128) {
        int i = (b - NB) * 256 + t;   // 32768 entries
        int n = i >> 7, k = i & 127;
        float v = (n < 128) ? Wl[k * 128 + n] : Wr[k * 128 + (n - 128)];
        Wb[i] = f2bf(v);
    } else {
        int i = (b - NB - 128) * 256 + t;  // 4096 entries: Wb2[n][k], n in [0,32)
        int n = i >> 7, k = i & 127;
        float v = (n < 16) ? Wl2[k * 16 + n] : Wr2[k * 16 + (n - 16)];
        Wb2[i] = f2bf(v);
    }
}

// ---------- fused: XCD-partitioned padded fill (blocks 0..FILLB) || gemm1 MFMA (FILLB..FILLB+GB) ----------
// Fill FIRST: its atomic/scatter latency stream starts at t=0, gemm1's dense MFMA backfills.
// Partition: block b handles edge-chunk b>>3, but ONLY edges with dst in range (b&7).
// Round-robin block->XCD puts range r's esrcPad slice (0.8 MB u16) + cnt slice in ONE XCD's L2
// (measured: fill 85 -> 71.5 us, round 1). nt loads only on read-once streams (ei, x);
// xlb/xr stores stay cached (l1 re-reads them -> round-1's nt xr store cost ~15 us, reverted).
__global__ __launch_bounds__(256) void fill_gemm1(const int* __restrict__ ei,
                                                  int* __restrict__ cnt,
                                                  unsigned short* __restrict__ esrcPad,
                                                  const float* __restrict__ x,
                                                  const unsigned short* __restrict__ Wb,
                                                  unsigned short* __restrict__ xlb,
                                                  float* __restrict__ xr) {
    __shared__ unsigned short As[GM][136];   // gemm1 path only; pad 128->136
    int t = threadIdx.x;
    if (blockIdx.x < FILLB) {   // ---- fill path ----
        int chunk = blockIdx.x >> 3;
        int r = blockIdx.x & 7;          // dst-range == heuristic XCD id
        int i = chunk * 256 + t;
        if (i >= EE / 4) return;
        i32x4 ss = __builtin_nontemporal_load(((const i32x4*)ei) + i);
        i32x4 dd = __builtin_nontemporal_load(((const i32x4*)(ei + EE)) + i);
        int lo = r * RANGE;
        int p;
        if ((unsigned)(dd[0] - lo) < RANGE) {
            p = atomicAdd(&cnt[dd[0]], 1);
            esrcPad[(size_t)dd[0] * PAD + p] = (unsigned short)ss[0];
        }
        if ((unsigned)(dd[1] - lo) < RANGE) {
            p = atomicAdd(&cnt[dd[1]], 1);
            esrcPad[(size_t)dd[1] * PAD + p] = (unsigned short)ss[1];
        }
        if ((unsigned)(dd[2] - lo) < RANGE) {
            p = atomicAdd(&cnt[dd[2]], 1);
            esrcPad[(size_t)dd[2] * PAD + p] = (unsigned short)ss[2];
        }
        if ((unsigned)(dd[3] - lo) < RANGE) {
            p = atomicAdd(&cnt[dd[3]], 1);
            esrcPad[(size_t)dd[3] * PAD + p] = (unsigned short)ss[3];
        }
        return;
    }
    // ---- gemm1 path: 32 nodes x 256 cols, 4 waves; m89-verified 16x16x32 bf16 layouts ----
    int n0 = (blockIdx.x - FILLB) * GM;
    {   // stage: 32 rows x 128 ch fp32 -> bf16 LDS (nt: x is read-once, keep L2 for scatter)
        int row = t >> 3, seg = t & 7;
        int nsrc = n0 + row < NN ? n0 + row : NN - 1;   // clamp: safe read, store guarded
        const f32x4* xp = (const f32x4*)(x + (size_t)nsrc * DIN + 16 * seg);
        f32x4 v0 = __builtin_nontemporal_load(xp);
        f32x4 v1 = __builtin_nontemporal_load(xp + 1);
        f32x4 v2 = __builtin_nontemporal_load(xp + 2);
        f32x4 v3 = __builtin_nontemporal_load(xp + 3);
        uint4 p0 = make_uint4(pack2bf(v0[0], v0[1]), pack2bf(v0[2], v0[3]),
                              pack2bf(v1[0], v1[1]), pack2bf(v1[2], v1[3]));
        uint4 p1 = make_uint4(pack2bf(v2[0], v2[1]), pack2bf(v2[2], v2[3]),
                              pack2bf(v3[0], v3[1]), pack2bf(v3[2], v3[3]));
        *(uint4*)&As[row][16 * seg]     = p0;
        *(uint4*)&As[row][16 * seg + 8] = p1;
    }
    __syncthreads();
    int lane = t & 63, w = t >> 6;
    int m = lane & 15, quad = lane >> 4;
    f32x4 acc[2][4];
#pragma unroll
    for (int mt = 0; mt < 2; ++mt)
#pragma unroll
        for (int nt = 0; nt < 4; ++nt) acc[mt][nt] = (f32x4){0.f, 0.f, 0.f, 0.f};
#pragma unroll
    for (int ks = 0; ks < 4; ++ks) {
        int k = 32 * ks + 8 * quad;
        bf16x8 a0 = *(const bf16x8*)&As[m][k];
        bf16x8 a1 = *(const bf16x8*)&As[16 + m][k];
#pragma unroll
        for (int nt = 0; nt < 4; ++nt) {
            int n = 64 * w + 16 * nt + m;
            bf16x8 b = *(const bf16x8*)(Wb + (size_t)n * 128 + k);
            acc[0][nt] = __builtin_amdgcn_mfma_f32_16x16x32_bf16(a0, b, acc[0][nt], 0, 0, 0);
            acc[1][nt] = __builtin_amdgcn_mfma_f32_16x16x32_bf16(a1, b, acc[1][nt], 0, 0, 0);
        }
    }
#pragma unroll
    for (int mt = 0; mt < 2; ++mt) {
#pragma unroll
        for (int nt = 0; nt < 4; ++nt) {
            int col = 64 * w + 16 * nt + m;       // wave-uniform half selection
            int rbase = n0 + 16 * mt + 4 * quad;
            if (col < 128) {
#pragma unroll
                for (int r = 0; r < 4; ++r) {
                    int row = rbase + r;
                    if (row < NN) xlb[(size_t)row * DIN + col] = f2bf(acc[mt][nt][r]);
                }
            } else {
#pragma unroll
                for (int r = 0; r < 4; ++r) {
                    int row = rbase + r;
                    if (row < NN) xr[(size_t)row * DIN + (col - 128)] = acc[mt][nt][r];
                }
            }
        }
    }
}

// ---------- layer-1 fused: logits + segment softmax + gather + bias + ELU -> bf16 hb ----------
// one wave per dst; quarter-wave per edge slot: 16 lanes x 8 bf16 channels.
__global__ __launch_bounds__(256) void l1_fused(const unsigned short* __restrict__ esrcPad,
                                                const int* __restrict__ cnt,
                                                const unsigned short* __restrict__ xlb,
                                                const float* __restrict__ xr,
                                                const float* __restrict__ att,
                                                const float* __restrict__ bias,
                                                unsigned short* __restrict__ hb) {
    int d = blockIdx.x * 4 + (threadIdx.x >> 6);    // NN % 4 == 0
    int lane = threadIdx.x & 63;
    int quarter = lane >> 4;
    int q16 = lane & 15;        // channel octet [8*q16, 8*q16+8)
    int rs = d * PAD;
    int re = rs + cnt[d];       // cnt >= 1 (self-loop)
    int last = re - 1;
    float4 xr0 = ((const float4*)(xr + (size_t)d * DIN))[2 * q16];
    float4 xr1 = ((const float4*)(xr + (size_t)d * DIN))[2 * q16 + 1];
    float4 at0 = ((const float4*)att)[2 * q16];
    float4 at1 = ((const float4*)att)[2 * q16 + 1];
    float4 a0 = make_float4(0.f, 0.f, 0.f, 0.f);
    float4 a1 = make_float4(0.f, 0.f, 0.f, 0.f);
    float l = 0.f;
    int slot = rs + quarter;
    int c0 = slot < last ? slot : last;
    int s0 = esrcPad[c0];
    int c1 = slot + 4 < last ? slot + 4 : last;
    int s1 = esrcPad[c1];
    uint4 row = ((const uint4*)(xlb + (size_t)s0 * DIN))[q16];
    for (; slot < re; slot += 4) {
        uint4 cur = row;
        int c2 = slot + 8 < last ? slot + 8 : last;
        int s2 = esrcPad[c2];                                 // 2 ahead
        row = ((const uint4*)(xlb + (size_t)s1 * DIN))[q16];  // 1 ahead
        s1 = s2;
        float f0 = bflo(cur.x), f1 = bfhi(cur.x);
        float f2 = bflo(cur.y), f3 = bfhi(cur.y);
        float f4 = bflo(cur.z), f5 = bfhi(cur.z);
        float f6 = bflo(cur.w), f7 = bfhi(cur.w);
        float v0 = f0 + xr0.x; v0 = fmaxf(v0, NEG * v0);
        float v1 = f1 + xr0.y; v1 = fmaxf(v1, NEG * v1);
        float v2 = f2 + xr0.z; v2 = fmaxf(v2, NEG * v2);
        float v3 = f3 + xr0.w; v3 = fmaxf(v3, NEG * v3);
        float v4 = f4 + xr1.x; v4 = fmaxf(v4, NEG * v4);
        float v5 = f5 + xr1.y; v5 = fmaxf(v5, NEG * v5);
        float v6 = f6 + xr1.z; v6 = fmaxf(v6, NEG * v6);
        float v7 = f7 + xr1.w; v7 = fmaxf(v7, NEG * v7);
        float w = at0.x * v0 + at0.y * v1 + at0.z * v2 + at0.w * v3
                + at1.x * v4 + at1.y * v5 + at1.z * v6 + at1.w * v7;
        w += __shfl_xor(w, 1);          // full 16-ch head logit (lane pair)
        float p = __expf(w);
        a0.x += p * f0; a0.y += p * f1; a0.z += p * f2; a0.w += p * f3;
        a1.x += p * f4; a1.y += p * f5; a1.z += p * f6; a1.w += p * f7;
        l += p;
    }
#pragma unroll
    for (int off = 16; off < 64; off <<= 1) {
        a0.x += __shfl_xor(a0.x, off); a0.y += __shfl_xor(a0.y, off);
        a0.z += __shfl_xor(a0.z, off); a0.w += __shfl_xor(a0.w, off);
        a1.x += __shfl_xor(a1.x, off); a1.y += __shfl_xor(a1.y, off);
        a1.z += __shfl_xor(a1.z, off); a1.w += __shfl_xor(a1.w, off);
        l += __shfl_xor(l, off);
    }
    if (quarter == 0) {
        float inv = 1.f / l;
        float4 b0 = ((const float4*)bias)[2 * q16];
        float4 b1 = ((const float4*)bias)[2 * q16 + 1];
        float4 o0, o1;
        o0.x = a0.x * inv + b0.x; o0.x = o0.x > 0.f ? o0.x : expm1f(o0.x);
        o0.y = a0.y * inv + b0.y; o0.y = o0.y > 0.f ? o0.y : expm1f(o0.y);
        o0.z = a0.z * inv + b0.z; o0.z = o0.z > 0.f ? o0.z : expm1f(o0.z);
        o0.w = a0.w * inv + b0.w; o0.w = o0.w > 0.f ? o0.w : expm1f(o0.w);
        o1.x = a1.x * inv + b1.x; o1.x = o1.x > 0.f ? o1.x : expm1f(o1.x);
        o1.y = a1.y * inv + b1.y; o1.y = o1.y > 0.f ? o1.y : expm1f(o1.y);
        o1.z = a1.z * inv + b1.z; o1.z = o1.z > 0.f ? o1.z : expm1f(o1.z);
        o1.w = a1.w * inv + b1.w; o1.w = o1.w > 0.f ? o1.w : expm1f(o1.w);
        // store bf16 row (halves write BW; gemm2 reads bf16 directly for MFMA)
        uint4 pk = make_uint4(pack2bf(o0.x, o0.y), pack2bf(o0.z, o0.w),
                              pack2bf(o1.x, o1.y), pack2bf(o1.z, o1.w));
        ((uint4*)(hb + (size_t)d * DIN))[q16] = pk;
    }
}

// ---------- layer-2 GEMM via MFMA: [xl2 | xr2] = hb @ [Wl2 | Wr2] ----------
// 32 nodes x 32 cols per block, 4 waves: wave w -> (mt=w&1, nt=w>>1) 16x16 tile.
__global__ __launch_bounds__(256) void gemm2(const unsigned short* __restrict__ hb,
                                             const unsigned short* __restrict__ Wb2,
                                             float* __restrict__ xl2, float* __restrict__ xr2) {
    __shared__ unsigned short As[GM][136];
    int t = threadIdx.x;
    int n0 = blockIdx.x * GM;
    {   // stage 32 bf16 rows (256B each): 8 threads/row x 2 uint4
        int row = t >> 3, s8 = t & 7;
        int nsrc = n0 + row < NN ? n0 + row : NN - 1;
        const uint4* src = (const uint4*)(hb + (size_t)nsrc * DIN);
        *(uint4*)&As[row][8 * s8]      = src[s8];
        *(uint4*)&As[row][8 * s8 + 64] = src[s8 + 8];
    }
    __syncthreads();
    int lane = t & 63, w = t >> 6;
    int m = lane & 15, quad = lane >> 4;
    int mt = w & 1, nt = w >> 1;
    f32x4 acc = (f32x4){0.f, 0.f, 0.f, 0.f};
#pragma unroll
    for (int ks = 0; ks < 4; ++ks) {
        int k = 32 * ks + 8 * quad;
        bf16x8 a = *(const bf16x8*)&As[16 * mt + m][k];
        bf16x8 b = *(const bf16x8*)(Wb2 + (size_t)(16 * nt + m) * 128 + k);
        acc = __builtin_amdgcn_mfma_f32_16x16x32_bf16(a, b, acc, 0, 0, 0);
    }
    // D: col=lane&15 (n within tile), row=quad*4+r (m within tile)
    float* __restrict__ dst = (nt == 0) ? xl2 : xr2;
#pragma unroll
    for (int r = 0; r < 4; ++r) {
        int node = n0 + 16 * mt + 4 * quad + r;
        if (node < NN) dst[(size_t)node * DOUT + m] = acc[r];
    }
}

// ---------- layer-2 fused: softmax + gather + bias + log_softmax ----------
__global__ __launch_bounds__(256) void l2_fused(const unsigned short* __restrict__ esrcPad,
                                                const int* __restrict__ cnt,
                                                const float* __restrict__ xl,
                                                const float* __restrict__ xr,
                                                const float* __restrict__ att,
                                                const float* __restrict__ bias,
                                                float* __restrict__ out) {
    int d = blockIdx.x * 4 + (threadIdx.x >> 6);    // NN % 4 == 0
    int lane = threadIdx.x & 63;
    int sl = lane >> 2;     // edge slot group 0..15
    int q = lane & 3;       // channel quad
    int rs = d * PAD;
    int re = rs + cnt[d];
    int last = re - 1;
    float4 xrq = ((const float4*)(xr + (size_t)d * DOUT))[q];
    float4 atq = ((const float4*)att)[q];
    float4 acc = make_float4(0.f, 0.f, 0.f, 0.f);
    float l = 0.f;
    int slot = rs + sl;
    int c0 = slot < last ? slot : last;
    int s0 = esrcPad[c0];
    for (; slot < re; slot += 16) {
        int c1 = slot + 16 < last ? slot + 16 : last;
        int s1 = esrcPad[c1];
        float4 cur = ((const float4*)(xl + (size_t)s0 * DOUT))[q];
        s0 = s1;
        float v0 = cur.x + xrq.x; v0 = fmaxf(v0, NEG * v0);
        float v1 = cur.y + xrq.y; v1 = fmaxf(v1, NEG * v1);
        float v2 = cur.z + xrq.z; v2 = fmaxf(v2, NEG * v2);
        float v3 = cur.w + xrq.w; v3 = fmaxf(v3, NEG * v3);
        float w = atq.x * v0 + atq.y * v1 + atq.z * v2 + atq.w * v3;
        w += __shfl_xor(w, 1);
        w += __shfl_xor(w, 2);          // full 16-ch logit
        float p = __expf(w);
        acc.x += p * cur.x; acc.y += p * cur.y;
        acc.z += p * cur.z; acc.w += p * cur.w;
        l += p;
    }
#pragma unroll
    for (int off = 4; off < 64; off <<= 1) {
        acc.x += __shfl_xor(acc.x, off);
        acc.y += __shfl_xor(acc.y, off);
        acc.z += __shfl_xor(acc.z, off);
        acc.w += __shfl_xor(acc.w, off);
        l += __shfl_xor(l, off);
    }
    float inv = 1.f / l;
    float4 b = ((const float4*)bias)[q];
    float4 v;
    v.x = acc.x * inv + b.x; v.y = acc.y * inv + b.y;
    v.z = acc.z * inv + b.z; v.w = acc.w * inv + b.w;
    float m = fmaxf(fmaxf(v.x, v.y), fmaxf(v.z, v.w));
    m = fmaxf(m, __shfl_xor(m, 1));
    m = fmaxf(m, __shfl_xor(m, 2));
    float es = __expf(v.x - m) + __expf(v.y - m) + __expf(v.z - m) + __expf(v.w - m);
    es += __shfl_xor(es, 1);
    es += __shfl_xor(es, 2);
    float lse = m + __logf(es);
    if (sl == 0) {
        ((float4*)(out + (size_t)d * DOUT))[q] = v;
        float4 ls;
        ls.x = v.x - lse; ls.y = v.y - lse; ls.z = v.z - lse; ls.w = v.w - lse;
        ((float4*)(out + (size_t)NN * DOUT + (size_t)d * DOUT))[q] = ls;
    }
}

extern "C" void kernel_launch(void* const* d_in, const int* in_sizes, int n_in,
                              void* d_out, int out_size, void* d_ws, size_t ws_size,
                              hipStream_t stream) {
    const float* x     = (const float*)d_in[0];
    const int*   ei    = (const int*)d_in[1];
    const float* Wl1   = (const float*)d_in[2];
    const float* Wr1   = (const float*)d_in[3];
    const float* att1  = (const float*)d_in[4];
    const float* bias1 = (const float*)d_in[5];
    const float* Wl2   = (const float*)d_in[6];
    const float* Wr2   = (const float*)d_in[7];
    const float* att2  = (const float*)d_in[8];
    const float* bias2 = (const float*)d_in[9];
    float* out = (float*)d_out;

    // ---- workspace layout ----
    float* xr1    = (float*)d_ws;                    // NN*128 fp32
    float* xl2    = xr1 + (size_t)NN * DIN;          // NN*16
    float* xr2    = xl2 + (size_t)NN * DOUT;         // NN*16
    unsigned short* xlb = (unsigned short*)(xr2 + (size_t)NN * DOUT); // NN*128 bf16
    unsigned short* hb  = xlb + (size_t)NN * DIN;    // NN*128 bf16
    unsigned short* Wb  = hb + (size_t)NN * DIN;     // 256*128 bf16
    unsigned short* Wb2 = Wb + 256 * 128;            // 32*128 bf16
    unsigned short* esrcPad = Wb2 + 32 * 128;        // NN*64 padded CSR (u16: src < 50000 < 65536)
    int*   cnt    = (int*)(esrcPad + (size_t)NN * PAD);  // NN (byte offset multiple of 4)

    const int B = 256;
    init_wcvt<<<NB + 144, B, 0, stream>>>(cnt, esrcPad, Wl1, Wr1, Wb, Wl2, Wr2, Wb2);
    fill_gemm1<<<FILLB + GB, B, 0, stream>>>(ei, cnt, esrcPad, x, Wb, xlb, xr1);

    l1_fused<<<NN / 4, B, 0, stream>>>(esrcPad, cnt, xlb, xr1, att1, bias1, hb);

    gemm2<<<GB, B, 0, stream>>>(hb, Wb2, xl2, xr2);

    l2_fused<<<NN / 4, B, 0, stream>>>(esrcPad, cnt, xl2, xr2, att2, bias2, out);
}